// Round 19
// baseline (5955.005 us; speedup 1.0000x reference)
//
#include <hip/hip_runtime.h>
#include <hip/hip_bf16.h>

typedef __bf16 bf16_t;
typedef __bf16 bf16x4 __attribute__((ext_vector_type(4)));
typedef __bf16 bf16x8 __attribute__((ext_vector_type(8)));
typedef float f32x4 __attribute__((ext_vector_type(4)));

static __device__ __forceinline__ float warp_sum(float v) {
#pragma unroll
    for (int off = 32; off > 0; off >>= 1) v += __shfl_xor(v, off, 64);
    return v;
}

// ---------------- mask encoding/layout detection ----------------
// Detected on real data (round 18): esz=4 (int32), layout=[B,T], normal.
// Detection kept for robustness; canonicalize to byte padc[b*1024+t].
__global__ void mask_detect_kernel(const unsigned char* __restrict__ m,
                                   int* __restrict__ flags) {
    __shared__ int cnt[256];
    int t = threadIdx.x;
    int c = 0;
    for (int i = t; i < 32768; i += 256) c += (m[i] != 0);
    cnt[t] = c;
    __syncthreads();
    for (int o = 128; o > 0; o >>= 1) {
        if (t < o) cnt[t] += cnt[t + o];
        __syncthreads();
    }
    if (t != 0) return;
    int inv = cnt[0] > 16384;
    auto P = [&](long idx) {
        int v = m[idx] != 0;
        return inv ? !v : v;
    };
    int esz, layout;
    if (P(960)) { esz = 1; layout = 0; }
    else if (P(3840) | P(3841) | P(3842) | P(3843)) { esz = 4; layout = 0; }
    else if (P(7680) | P(7681) | P(7682) | P(7683) |
             P(7684) | P(7685) | P(7686) | P(7687)) { esz = 8; layout = 0; }
    else if (P(30720)) { esz = 1; layout = 1; }
    else {
        long b0 = 4L * 30720;
        if (P(b0) | P(b0 + 1) | P(b0 + 2) | P(b0 + 3)) { esz = 4; layout = 1; }
        else { esz = 8; layout = 1; }
    }
    flags[0] = esz; flags[1] = layout; flags[2] = inv;
}

__global__ __launch_bounds__(256) void mask_canon_kernel(const unsigned char* __restrict__ m,
                                                         const int* __restrict__ flags,
                                                         unsigned char* __restrict__ padc) {
    int e = blockIdx.x * 256 + threadIdx.x;  // [0, 32768) = b*1024 + t
    int esz = flags[0], layout = flags[1], inv = flags[2];
    int b = e >> 10, t = e & 1023;
    long se = layout ? ((long)t * 32 + b) : (long)e;
    unsigned char acc = 0;
    for (int k = 0; k < esz; ++k) acc |= m[se * esz + k];
    int padded = (acc != 0);
    if (inv) padded = !padded;
    padc[e] = (unsigned char)padded;
}

// ---------------- f32 copy (x -> h residual) ----------------
__global__ __launch_bounds__(256) void copy_f32_kernel(const float* __restrict__ src,
                                                       float* __restrict__ dst) {
    size_t i = ((size_t)blockIdx.x * 256 + threadIdx.x) * 4;
    *reinterpret_cast<float4*>(&dst[i]) = *reinterpret_cast<const float4*>(&src[i]);
}

// ---------------- f32 -> bf16 weight conversion ----------------
__global__ __launch_bounds__(256) void cvt_bf16_kernel(const float* __restrict__ src,
                                                       bf16_t* __restrict__ dst) {
    size_t i = ((size_t)blockIdx.x * 256 + threadIdx.x) * 4;
    float4 v = *reinterpret_cast<const float4*>(&src[i]);
    bf16x4 o;
    o[0] = (bf16_t)v.x; o[1] = (bf16_t)v.y; o[2] = (bf16_t)v.z; o[3] = (bf16_t)v.w;
    *reinterpret_cast<bf16x4*>(&dst[i]) = o;
}

// ---------------- LayerNorm (one wave per token, D=512) ----------------
__global__ __launch_bounds__(256) void ln_kernel(const float* __restrict__ h,
                                                 const float* __restrict__ g,
                                                 const float* __restrict__ bta,
                                                 bf16_t* __restrict__ y) {
    int wave = threadIdx.x >> 6, lane = threadIdx.x & 63;
    size_t t = (size_t)blockIdx.x * 4 + wave;
    const float* hp = h + t * 512 + lane * 8;
    float v[8];
    *reinterpret_cast<float4*>(&v[0]) = *reinterpret_cast<const float4*>(hp);
    *reinterpret_cast<float4*>(&v[4]) = *reinterpret_cast<const float4*>(hp + 4);
    float s = 0.f;
#pragma unroll
    for (int i = 0; i < 8; ++i) s += v[i];
    s = warp_sum(s);
    float mean = s * (1.0f / 512.0f);
    float sq = 0.f;
#pragma unroll
    for (int i = 0; i < 8; ++i) { float d = v[i] - mean; sq += d * d; }
    sq = warp_sum(sq);
    float rstd = rsqrtf(sq * (1.0f / 512.0f) + 1e-5f);
    float gv[8], bv[8];
    *reinterpret_cast<float4*>(&gv[0]) = *reinterpret_cast<const float4*>(&g[lane * 8]);
    *reinterpret_cast<float4*>(&gv[4]) = *reinterpret_cast<const float4*>(&g[lane * 8 + 4]);
    *reinterpret_cast<float4*>(&bv[0]) = *reinterpret_cast<const float4*>(&bta[lane * 8]);
    *reinterpret_cast<float4*>(&bv[4]) = *reinterpret_cast<const float4*>(&bta[lane * 8 + 4]);
    bf16x8 ov;
#pragma unroll
    for (int i = 0; i < 8; ++i)
        ov[i] = (bf16_t)((v[i] - mean) * rstd * gv[i] + bv[i]);
    *reinterpret_cast<bf16x8*>(&y[t * 512 + lane * 8]) = ov;
}

// ---------------- GEMM: C[M,N] = A[M,K] @ Bw[N,K]^T (+bias, modes) --------
template <int MODE>
__global__ __launch_bounds__(256) void gemm_bt_kernel(
    const bf16_t* __restrict__ A, const bf16_t* __restrict__ Bw,
    const float* __restrict__ bias, bf16_t* __restrict__ Cbf,
    float* __restrict__ Cacc, int M, int N, int K, int lda, int ldb) {
    constexpr int BK = 64, PAD = 8, LDT = BK + PAD;
    __shared__ bf16_t sA[128 * LDT];
    __shared__ bf16_t sB[128 * LDT];
    const int tid = threadIdx.x;
    const int row0 = blockIdx.x * 128;
    const int col0 = blockIdx.y * 128;
    const int wave = tid >> 6, lane = tid & 63;
    const int wm = (wave >> 1) * 64, wn = (wave & 1) * 64;
    const int fr = lane & 15;
    const int fk = (lane >> 4) * 8;
    f32x4 acc[4][4] = {};
    for (int k0 = 0; k0 < K; k0 += BK) {
#pragma unroll
        for (int p = 0; p < 4; ++p) {
            int c = p * 256 + tid;
            int r = c >> 3, c8 = (c & 7) * 8;
            *reinterpret_cast<uint4*>(&sA[r * LDT + c8]) =
                *reinterpret_cast<const uint4*>(&A[(size_t)(row0 + r) * lda + k0 + c8]);
            *reinterpret_cast<uint4*>(&sB[r * LDT + c8]) =
                *reinterpret_cast<const uint4*>(&Bw[(size_t)(col0 + r) * ldb + k0 + c8]);
        }
        __syncthreads();
#pragma unroll
        for (int kk = 0; kk < BK; kk += 32) {
            bf16x8 af[4], bfr[4];
#pragma unroll
            for (int m = 0; m < 4; ++m)
                af[m] = *reinterpret_cast<const bf16x8*>(&sA[(wm + m * 16 + fr) * LDT + kk + fk]);
#pragma unroll
            for (int n = 0; n < 4; ++n)
                bfr[n] = *reinterpret_cast<const bf16x8*>(&sB[(wn + n * 16 + fr) * LDT + kk + fk]);
#pragma unroll
            for (int m = 0; m < 4; ++m)
#pragma unroll
                for (int n = 0; n < 4; ++n)
                    acc[m][n] = __builtin_amdgcn_mfma_f32_16x16x32_bf16(af[m], bfr[n], acc[m][n], 0, 0, 0);
        }
        __syncthreads();
    }
    const int cq = lane & 15;
    const int rq = (lane >> 4) * 4;
#pragma unroll
    for (int m = 0; m < 4; ++m) {
#pragma unroll
        for (int n = 0; n < 4; ++n) {
            int gc = col0 + wn + n * 16 + cq;
            float bv = bias ? bias[gc] : 0.f;
#pragma unroll
            for (int r = 0; r < 4; ++r) {
                int gr = row0 + wm + m * 16 + rq + r;
                float val = acc[m][n][r] + bv;
                if constexpr (MODE == 1) val = val > 0.f ? val : 0.f;
                if constexpr (MODE == 2) {
                    Cacc[(size_t)gr * N + gc] += val;
                } else {
                    Cbf[(size_t)gr * N + gc] = (bf16_t)val;
                }
            }
        }
    }
}

// ---------------- banded attention, batch-first rows, |i-j|<=10 -----------
__global__ __launch_bounds__(256) void attn_kernel(const bf16_t* __restrict__ qkv,
                                                   const unsigned char* __restrict__ pad,
                                                   bf16_t* __restrict__ o) {
    int wave = threadIdx.x >> 6, lane = threadIdx.x & 63;
    int w = blockIdx.x * 4 + wave;
    int i = w & 1023, hh = (w >> 10) & 7, b = w >> 13;
    const size_t base = (size_t)(b << 10) * 1536;
    float qd = (float)qkv[base + (size_t)i * 1536 + (hh << 6) + lane];

    unsigned valid = 0u;
#pragma unroll
    for (int jj = 0; jj < 21; ++jj) {
        int j = i - 10 + jj;
        if (j >= 0 && j < 1024 && pad[(b << 10) + j] == 0) valid |= (1u << jj);
    }

    float od;
    if (valid == 0u) {
        // fully-masked row: softmax over raw scores of all 1024 keys
        float m = -3.0e38f, den = 0.f, num = 0.f;
        for (int j = 0; j < 1024; ++j) {
            size_t rowj = base + (size_t)j * 1536;
            float kd = (float)qkv[rowj + 512 + (hh << 6) + lane];
            float s = warp_sum(qd * kd) * 0.125f;
            float vd = (float)qkv[rowj + 1024 + (hh << 6) + lane];
            float mn = fmaxf(m, s);
            float corr = __expf(m - mn);
            float e = __expf(s - mn);
            den = den * corr + e;
            num = num * corr + e * vd;
            m = mn;
        }
        od = num / den;
    } else {
        float sc[21];
#pragma unroll
        for (int jj = 0; jj < 21; ++jj) {
            int j = i - 10 + jj;
            int jc = j < 0 ? 0 : (j > 1023 ? 1023 : j);
            float kd = (float)qkv[base + (size_t)jc * 1536 + 512 + (hh << 6) + lane];
            sc[jj] = warp_sum(qd * kd) * 0.125f;
        }
        float mx = -3.0e38f;
#pragma unroll
        for (int jj = 0; jj < 21; ++jj)
            if ((valid >> jj) & 1u) mx = fmaxf(mx, sc[jj]);
        float den = 0.f;
#pragma unroll
        for (int jj = 0; jj < 21; ++jj) {
            float e = ((valid >> jj) & 1u) ? __expf(sc[jj] - mx) : 0.f;
            sc[jj] = e;
            den += e;
        }
        float num = 0.f;
#pragma unroll
        for (int jj = 0; jj < 21; ++jj) {
            int j = i - 10 + jj;
            int jc = j < 0 ? 0 : (j > 1023 ? 1023 : j);
            float vd = (float)qkv[base + (size_t)jc * 1536 + 1024 + (hh << 6) + lane];
            num += sc[jj] * vd;
        }
        od = num / den;
    }
    o[(size_t)((b << 10) + i) * 512 + (hh << 6) + lane] = (bf16_t)od;
}

// ---------------- classifier (f32 out, flat rows) ----------------
__global__ __launch_bounds__(256) void cls_kernel(const float* __restrict__ h,
                                                  const float* __restrict__ Wc,
                                                  const float* __restrict__ bc,
                                                  float* __restrict__ out) {
    int wave = threadIdx.x >> 6, lane = threadIdx.x & 63;
    size_t t = (size_t)blockIdx.x * 4 + wave;
    float v[8];
    *reinterpret_cast<float4*>(&v[0]) = *reinterpret_cast<const float4*>(&h[t * 512 + lane * 8]);
    *reinterpret_cast<float4*>(&v[4]) = *reinterpret_cast<const float4*>(&h[t * 512 + lane * 8 + 4]);
#pragma unroll
    for (int c = 0; c < 5; ++c) {
        float w[8];
        *reinterpret_cast<float4*>(&w[0]) = *reinterpret_cast<const float4*>(&Wc[c * 512 + lane * 8]);
        *reinterpret_cast<float4*>(&w[4]) = *reinterpret_cast<const float4*>(&Wc[c * 512 + lane * 8 + 4]);
        float p = 0.f;
#pragma unroll
        for (int i = 0; i < 8; ++i) p += v[i] * w[i];
        p = warp_sum(p);
        if (lane == 0) out[t * 5 + c] = p + bc[c];
    }
}

extern "C" void kernel_launch(void* const* d_in, const int* in_sizes, int n_in,
                              void* d_out, int out_size, void* d_ws, size_t ws_size,
                              hipStream_t stream) {
    const float* x = (const float*)d_in[0];
    const unsigned char* mask_raw = (const unsigned char*)d_in[1];
    const float* Wqkv = (const float*)d_in[2];
    const float* bqkv = (const float*)d_in[3];
    const float* Wo = (const float*)d_in[4];
    const float* bo = (const float*)d_in[5];
    const float* ln1_g = (const float*)d_in[6];
    const float* ln1_b = (const float*)d_in[7];
    const float* W1 = (const float*)d_in[8];
    const float* b1 = (const float*)d_in[9];
    const float* W2 = (const float*)d_in[10];
    const float* b2 = (const float*)d_in[11];
    const float* ln2_g = (const float*)d_in[12];
    const float* ln2_b = (const float*)d_in[13];
    const float* Wc = (const float*)d_in[14];
    const float* bc = (const float*)d_in[15];

    constexpr int M = 32 * 1024;
    constexpr size_t MiB = 1 << 20;
    char* ws = (char*)d_ws;
    float* h = (float*)ws;
    bf16_t* yo = (bf16_t*)(ws + 64 * MiB);
    bf16_t* big = (bf16_t*)(ws + 96 * MiB);
    bf16_t* wq = (bf16_t*)(ws + 192 * MiB);
    bf16_t* wo = (bf16_t*)(ws + 195 * MiB);
    bf16_t* w1 = (bf16_t*)(ws + 196 * MiB);
    bf16_t* w2 = (bf16_t*)(ws + 200 * MiB);
    unsigned char* padc = (unsigned char*)(ws + 204 * MiB);   // 32 KiB
    int* flags = (int*)(ws + 204 * MiB + 64 * 1024);

    mask_detect_kernel<<<1, 256, 0, stream>>>(mask_raw, flags);
    mask_canon_kernel<<<M / 256, 256, 0, stream>>>(mask_raw, flags, padc);

    copy_f32_kernel<<<M * 512 / (256 * 4), 256, 0, stream>>>(x, h);
    cvt_bf16_kernel<<<2 * 1536 * 512 / 1024, 256, 0, stream>>>(Wqkv, wq);
    cvt_bf16_kernel<<<2 * 512 * 512 / 1024, 256, 0, stream>>>(Wo, wo);
    cvt_bf16_kernel<<<2 * 2048 * 512 / 1024, 256, 0, stream>>>(W1, w1);
    cvt_bf16_kernel<<<2 * 512 * 2048 / 1024, 256, 0, stream>>>(W2, w2);

    for (int l = 0; l < 2; ++l) {
        ln_kernel<<<M / 4, 256, 0, stream>>>(h, ln1_g + l * 512, ln1_b + l * 512, yo);
        gemm_bt_kernel<0><<<dim3(M / 128, 12), 256, 0, stream>>>(
            yo, wq + (size_t)l * 1536 * 512, bqkv + l * 1536, big, nullptr, M, 1536, 512, 512, 512);
        attn_kernel<<<M * 8 / 4, 256, 0, stream>>>(big, padc, yo);
        gemm_bt_kernel<2><<<dim3(M / 128, 4), 256, 0, stream>>>(
            yo, wo + (size_t)l * 512 * 512, bo + l * 512, nullptr, h, M, 512, 512, 512, 512);
        ln_kernel<<<M / 4, 256, 0, stream>>>(h, ln2_g + l * 512, ln2_b + l * 512, yo);
        for (int half = 0; half < 2; ++half) {
            gemm_bt_kernel<1><<<dim3(M / 128, 8), 256, 0, stream>>>(
                yo, w1 + (size_t)l * 2048 * 512 + (size_t)half * 1024 * 512,
                b1 + l * 2048 + half * 1024, big, nullptr, M, 1024, 512, 512, 512);
            gemm_bt_kernel<2><<<dim3(M / 128, 4), 256, 0, stream>>>(
                big, w2 + (size_t)l * 512 * 2048 + (size_t)half * 1024,
                half == 0 ? b2 + l * 512 : nullptr, nullptr, h, M, 512, 1024, 1024, 2048);
        }
    }
    cls_kernel<<<M / 4, 256, 0, stream>>>(h, Wc, bc, (float*)d_out);
}

// Round 20
// 1863.189 us; speedup vs baseline: 3.1961x; 3.1961x over previous
//
#include <hip/hip_runtime.h>
#include <hip/hip_bf16.h>

typedef __bf16 bf16_t;
typedef __bf16 bf16x4 __attribute__((ext_vector_type(4)));
typedef __bf16 bf16x8 __attribute__((ext_vector_type(8)));
typedef float f32x4 __attribute__((ext_vector_type(4)));

static __device__ __forceinline__ float warp_sum(float v) {
#pragma unroll
    for (int off = 32; off > 0; off >>= 1) v += __shfl_xor(v, off, 64);
    return v;
}

// ---------------- mask encoding/layout detection (verified: int32 [B,T]) ---
__global__ void mask_detect_kernel(const unsigned char* __restrict__ m,
                                   int* __restrict__ flags) {
    __shared__ int cnt[256];
    int t = threadIdx.x;
    int c = 0;
    for (int i = t; i < 32768; i += 256) c += (m[i] != 0);
    cnt[t] = c;
    __syncthreads();
    for (int o = 128; o > 0; o >>= 1) {
        if (t < o) cnt[t] += cnt[t + o];
        __syncthreads();
    }
    if (t != 0) return;
    int inv = cnt[0] > 16384;
    auto P = [&](long idx) {
        int v = m[idx] != 0;
        return inv ? !v : v;
    };
    int esz, layout;
    if (P(960)) { esz = 1; layout = 0; }
    else if (P(3840) | P(3841) | P(3842) | P(3843)) { esz = 4; layout = 0; }
    else if (P(7680) | P(7681) | P(7682) | P(7683) |
             P(7684) | P(7685) | P(7686) | P(7687)) { esz = 8; layout = 0; }
    else if (P(30720)) { esz = 1; layout = 1; }
    else {
        long b0 = 4L * 30720;
        if (P(b0) | P(b0 + 1) | P(b0 + 2) | P(b0 + 3)) { esz = 4; layout = 1; }
        else { esz = 8; layout = 1; }
    }
    flags[0] = esz; flags[1] = layout; flags[2] = inv;
}

__global__ __launch_bounds__(256) void mask_canon_kernel(const unsigned char* __restrict__ m,
                                                         const int* __restrict__ flags,
                                                         unsigned char* __restrict__ padc) {
    int e = blockIdx.x * 256 + threadIdx.x;  // [0, 32768) = b*1024 + t
    int esz = flags[0], layout = flags[1], inv = flags[2];
    int b = e >> 10, t = e & 1023;
    long se = layout ? ((long)t * 32 + b) : (long)e;
    unsigned char acc = 0;
    for (int k = 0; k < esz; ++k) acc |= m[se * esz + k];
    int padded = (acc != 0);
    if (inv) padded = !padded;
    padc[e] = (unsigned char)padded;
}

// ---------------- f32 copy (x -> h residual) ----------------
__global__ __launch_bounds__(256) void copy_f32_kernel(const float* __restrict__ src,
                                                       float* __restrict__ dst) {
    size_t i = ((size_t)blockIdx.x * 256 + threadIdx.x) * 4;
    *reinterpret_cast<float4*>(&dst[i]) = *reinterpret_cast<const float4*>(&src[i]);
}

// ---------------- f32 -> bf16 weight conversion ----------------
__global__ __launch_bounds__(256) void cvt_bf16_kernel(const float* __restrict__ src,
                                                       bf16_t* __restrict__ dst) {
    size_t i = ((size_t)blockIdx.x * 256 + threadIdx.x) * 4;
    float4 v = *reinterpret_cast<const float4*>(&src[i]);
    bf16x4 o;
    o[0] = (bf16_t)v.x; o[1] = (bf16_t)v.y; o[2] = (bf16_t)v.z; o[3] = (bf16_t)v.w;
    *reinterpret_cast<bf16x4*>(&dst[i]) = o;
}

// ---------------- LayerNorm (one wave per token, D=512) ----------------
__global__ __launch_bounds__(256) void ln_kernel(const float* __restrict__ h,
                                                 const float* __restrict__ g,
                                                 const float* __restrict__ bta,
                                                 bf16_t* __restrict__ y) {
    int wave = threadIdx.x >> 6, lane = threadIdx.x & 63;
    size_t t = (size_t)blockIdx.x * 4 + wave;
    const float* hp = h + t * 512 + lane * 8;
    float v[8];
    *reinterpret_cast<float4*>(&v[0]) = *reinterpret_cast<const float4*>(hp);
    *reinterpret_cast<float4*>(&v[4]) = *reinterpret_cast<const float4*>(hp + 4);
    float s = 0.f;
#pragma unroll
    for (int i = 0; i < 8; ++i) s += v[i];
    s = warp_sum(s);
    float mean = s * (1.0f / 512.0f);
    float sq = 0.f;
#pragma unroll
    for (int i = 0; i < 8; ++i) { float d = v[i] - mean; sq += d * d; }
    sq = warp_sum(sq);
    float rstd = rsqrtf(sq * (1.0f / 512.0f) + 1e-5f);
    float gv[8], bv[8];
    *reinterpret_cast<float4*>(&gv[0]) = *reinterpret_cast<const float4*>(&g[lane * 8]);
    *reinterpret_cast<float4*>(&gv[4]) = *reinterpret_cast<const float4*>(&g[lane * 8 + 4]);
    *reinterpret_cast<float4*>(&bv[0]) = *reinterpret_cast<const float4*>(&bta[lane * 8]);
    *reinterpret_cast<float4*>(&bv[4]) = *reinterpret_cast<const float4*>(&bta[lane * 8 + 4]);
    bf16x8 ov;
#pragma unroll
    for (int i = 0; i < 8; ++i)
        ov[i] = (bf16_t)((v[i] - mean) * rstd * gv[i] + bv[i]);
    *reinterpret_cast<bf16x8*>(&y[t * 512 + lane * 8]) = ov;
}

// ---------------- GEMM: C[M,N] = A[M,K] @ Bw[N,K]^T (+bias, modes) --------
template <int MODE>
__global__ __launch_bounds__(256) void gemm_bt_kernel(
    const bf16_t* __restrict__ A, const bf16_t* __restrict__ Bw,
    const float* __restrict__ bias, bf16_t* __restrict__ Cbf,
    float* __restrict__ Cacc, int M, int N, int K, int lda, int ldb) {
    constexpr int BK = 64, PAD = 8, LDT = BK + PAD;
    __shared__ bf16_t sA[128 * LDT];
    __shared__ bf16_t sB[128 * LDT];
    const int tid = threadIdx.x;
    const int row0 = blockIdx.x * 128;
    const int col0 = blockIdx.y * 128;
    const int wave = tid >> 6, lane = tid & 63;
    const int wm = (wave >> 1) * 64, wn = (wave & 1) * 64;
    const int fr = lane & 15;
    const int fk = (lane >> 4) * 8;
    f32x4 acc[4][4] = {};
    for (int k0 = 0; k0 < K; k0 += BK) {
#pragma unroll
        for (int p = 0; p < 4; ++p) {
            int c = p * 256 + tid;
            int r = c >> 3, c8 = (c & 7) * 8;
            *reinterpret_cast<uint4*>(&sA[r * LDT + c8]) =
                *reinterpret_cast<const uint4*>(&A[(size_t)(row0 + r) * lda + k0 + c8]);
            *reinterpret_cast<uint4*>(&sB[r * LDT + c8]) =
                *reinterpret_cast<const uint4*>(&Bw[(size_t)(col0 + r) * ldb + k0 + c8]);
        }
        __syncthreads();
#pragma unroll
        for (int kk = 0; kk < BK; kk += 32) {
            bf16x8 af[4], bfr[4];
#pragma unroll
            for (int m = 0; m < 4; ++m)
                af[m] = *reinterpret_cast<const bf16x8*>(&sA[(wm + m * 16 + fr) * LDT + kk + fk]);
#pragma unroll
            for (int n = 0; n < 4; ++n)
                bfr[n] = *reinterpret_cast<const bf16x8*>(&sB[(wn + n * 16 + fr) * LDT + kk + fk]);
#pragma unroll
            for (int m = 0; m < 4; ++m)
#pragma unroll
                for (int n = 0; n < 4; ++n)
                    acc[m][n] = __builtin_amdgcn_mfma_f32_16x16x32_bf16(af[m], bfr[n], acc[m][n], 0, 0, 0);
        }
        __syncthreads();
    }
    const int cq = lane & 15;
    const int rq = (lane >> 4) * 4;
#pragma unroll
    for (int m = 0; m < 4; ++m) {
#pragma unroll
        for (int n = 0; n < 4; ++n) {
            int gc = col0 + wn + n * 16 + cq;
            float bv = bias ? bias[gc] : 0.f;
#pragma unroll
            for (int r = 0; r < 4; ++r) {
                int gr = row0 + wm + m * 16 + rq + r;
                float val = acc[m][n][r] + bv;
                if constexpr (MODE == 1) val = val > 0.f ? val : 0.f;
                if constexpr (MODE == 2) {
                    Cacc[(size_t)gr * N + gc] += val;
                } else {
                    Cbf[(size_t)gr * N + gc] = (bf16_t)val;
                }
            }
        }
    }
}

// ---------------- per-(b,h,d) mean of V (fallback = uniform softmax) ------
__global__ __launch_bounds__(256) void vmean_kernel(const bf16_t* __restrict__ qkv,
                                                    float* __restrict__ vmean) {
    int gidx = blockIdx.x * 256 + threadIdx.x;  // [0, 32*512)
    int b = gidx >> 9, hd = gidx & 511;
    const bf16_t* p = qkv + (size_t)b * 1024 * 1536 + 1024 + hd;
    float s = 0.f;
    for (int t = 0; t < 1024; ++t) s += (float)p[(size_t)t * 1536];
    vmean[gidx] = s * (1.0f / 1024.0f);
}

// ---------------- banded attention, batch-first rows, |i-j|<=10 -----------
__global__ __launch_bounds__(256) void attn_kernel(const bf16_t* __restrict__ qkv,
                                                   const unsigned char* __restrict__ pad,
                                                   const float* __restrict__ vmean,
                                                   bf16_t* __restrict__ o) {
    int wave = threadIdx.x >> 6, lane = threadIdx.x & 63;
    int w = blockIdx.x * 4 + wave;
    int i = w & 1023, hh = (w >> 10) & 7, b = w >> 13;
    const size_t base = (size_t)(b << 10) * 1536;

    unsigned valid = 0u;
#pragma unroll
    for (int jj = 0; jj < 21; ++jj) {
        int j = i - 10 + jj;
        if (j >= 0 && j < 1024 && pad[(b << 10) + j] == 0) valid |= (1u << jj);
    }

    float od;
    if (valid == 0u) {
        // fully-masked row: f32 ref collapses to uniform over all keys = vmean
        od = vmean[((b << 3) + hh) * 64 + lane];
    } else {
        float qd = (float)qkv[base + (size_t)i * 1536 + (hh << 6) + lane];
        float sc[21];
#pragma unroll
        for (int jj = 0; jj < 21; ++jj) {
            int j = i - 10 + jj;
            int jc = j < 0 ? 0 : (j > 1023 ? 1023 : j);
            float kd = (float)qkv[base + (size_t)jc * 1536 + 512 + (hh << 6) + lane];
            sc[jj] = warp_sum(qd * kd) * 0.125f;
        }
        float mx = -3.0e38f;
#pragma unroll
        for (int jj = 0; jj < 21; ++jj)
            if ((valid >> jj) & 1u) mx = fmaxf(mx, sc[jj]);
        float den = 0.f;
#pragma unroll
        for (int jj = 0; jj < 21; ++jj) {
            float e = ((valid >> jj) & 1u) ? __expf(sc[jj] - mx) : 0.f;
            sc[jj] = e;
            den += e;
        }
        float num = 0.f;
#pragma unroll
        for (int jj = 0; jj < 21; ++jj) {
            int j = i - 10 + jj;
            int jc = j < 0 ? 0 : (j > 1023 ? 1023 : j);
            float vd = (float)qkv[base + (size_t)jc * 1536 + 1024 + (hh << 6) + lane];
            num += sc[jj] * vd;
        }
        od = num / den;
    }
    o[(size_t)((b << 10) + i) * 512 + (hh << 6) + lane] = (bf16_t)od;
}

// ---------------- classifier (f32 out, flat rows) ----------------
__global__ __launch_bounds__(256) void cls_kernel(const float* __restrict__ h,
                                                  const float* __restrict__ Wc,
                                                  const float* __restrict__ bc,
                                                  float* __restrict__ out) {
    int wave = threadIdx.x >> 6, lane = threadIdx.x & 63;
    size_t t = (size_t)blockIdx.x * 4 + wave;
    float v[8];
    *reinterpret_cast<float4*>(&v[0]) = *reinterpret_cast<const float4*>(&h[t * 512 + lane * 8]);
    *reinterpret_cast<float4*>(&v[4]) = *reinterpret_cast<const float4*>(&h[t * 512 + lane * 8 + 4]);
#pragma unroll
    for (int c = 0; c < 5; ++c) {
        float w[8];
        *reinterpret_cast<float4*>(&w[0]) = *reinterpret_cast<const float4*>(&Wc[c * 512 + lane * 8]);
        *reinterpret_cast<float4*>(&w[4]) = *reinterpret_cast<const float4*>(&Wc[c * 512 + lane * 8 + 4]);
        float p = 0.f;
#pragma unroll
        for (int i = 0; i < 8; ++i) p += v[i] * w[i];
        p = warp_sum(p);
        if (lane == 0) out[t * 5 + c] = p + bc[c];
    }
}

extern "C" void kernel_launch(void* const* d_in, const int* in_sizes, int n_in,
                              void* d_out, int out_size, void* d_ws, size_t ws_size,
                              hipStream_t stream) {
    const float* x = (const float*)d_in[0];
    const unsigned char* mask_raw = (const unsigned char*)d_in[1];
    const float* Wqkv = (const float*)d_in[2];
    const float* bqkv = (const float*)d_in[3];
    const float* Wo = (const float*)d_in[4];
    const float* bo = (const float*)d_in[5];
    const float* ln1_g = (const float*)d_in[6];
    const float* ln1_b = (const float*)d_in[7];
    const float* W1 = (const float*)d_in[8];
    const float* b1 = (const float*)d_in[9];
    const float* W2 = (const float*)d_in[10];
    const float* b2 = (const float*)d_in[11];
    const float* ln2_g = (const float*)d_in[12];
    const float* ln2_b = (const float*)d_in[13];
    const float* Wc = (const float*)d_in[14];
    const float* bc = (const float*)d_in[15];

    constexpr int M = 32 * 1024;
    constexpr size_t MiB = 1 << 20;
    char* ws = (char*)d_ws;
    float* h = (float*)ws;
    bf16_t* yo = (bf16_t*)(ws + 64 * MiB);
    bf16_t* big = (bf16_t*)(ws + 96 * MiB);
    bf16_t* wq = (bf16_t*)(ws + 192 * MiB);
    bf16_t* wo = (bf16_t*)(ws + 195 * MiB);
    bf16_t* w1 = (bf16_t*)(ws + 196 * MiB);
    bf16_t* w2 = (bf16_t*)(ws + 200 * MiB);
    unsigned char* padc = (unsigned char*)(ws + 204 * MiB);   // 32 KiB
    int* flags = (int*)(ws + 204 * MiB + 64 * 1024);
    float* vmean = (float*)(ws + 204 * MiB + 128 * 1024);     // 64 KiB

    mask_detect_kernel<<<1, 256, 0, stream>>>(mask_raw, flags);
    mask_canon_kernel<<<M / 256, 256, 0, stream>>>(mask_raw, flags, padc);

    copy_f32_kernel<<<M * 512 / (256 * 4), 256, 0, stream>>>(x, h);
    cvt_bf16_kernel<<<2 * 1536 * 512 / 1024, 256, 0, stream>>>(Wqkv, wq);
    cvt_bf16_kernel<<<2 * 512 * 512 / 1024, 256, 0, stream>>>(Wo, wo);
    cvt_bf16_kernel<<<2 * 2048 * 512 / 1024, 256, 0, stream>>>(W1, w1);
    cvt_bf16_kernel<<<2 * 512 * 2048 / 1024, 256, 0, stream>>>(W2, w2);

    for (int l = 0; l < 2; ++l) {
        ln_kernel<<<M / 4, 256, 0, stream>>>(h, ln1_g + l * 512, ln1_b + l * 512, yo);
        gemm_bt_kernel<0><<<dim3(M / 128, 12), 256, 0, stream>>>(
            yo, wq + (size_t)l * 1536 * 512, bqkv + l * 1536, big, nullptr, M, 1536, 512, 512, 512);
        vmean_kernel<<<32 * 512 / 256, 256, 0, stream>>>(big, vmean);
        attn_kernel<<<M * 8 / 4, 256, 0, stream>>>(big, padc, vmean, yo);
        gemm_bt_kernel<2><<<dim3(M / 128, 4), 256, 0, stream>>>(
            yo, wo + (size_t)l * 512 * 512, bo + l * 512, nullptr, h, M, 512, 512, 512, 512);
        ln_kernel<<<M / 4, 256, 0, stream>>>(h, ln2_g + l * 512, ln2_b + l * 512, yo);
        for (int half = 0; half < 2; ++half) {
            gemm_bt_kernel<1><<<dim3(M / 128, 8), 256, 0, stream>>>(
                yo, w1 + (size_t)l * 2048 * 512 + (size_t)half * 1024 * 512,
                b1 + l * 2048 + half * 1024, big, nullptr, M, 1024, 512, 512, 512);
            gemm_bt_kernel<2><<<dim3(M / 128, 4), 256, 0, stream>>>(
                big, w2 + (size_t)l * 512 * 2048 + (size_t)half * 1024,
                half == 0 ? b2 + l * 512 : nullptr, nullptr, h, M, 512, 1024, 1024, 2048);
        }
    }
    cls_kernel<<<M / 4, 256, 0, stream>>>(h, Wc, bc, (float*)d_out);
}